// Round 4
// baseline (405.311 us; speedup 1.0000x reference)
//
#include <hip/hip_runtime.h>
#include <hip/hip_bf16.h>
#include <math.h>

// N=50000 nodes, E=600000 edges, H=128.
#define HD 128
#define APAD 136   // LDS row stride in ushorts (+8 pad: 272 B rows, 16B-aligned, 2-way bank alias = free)

typedef short bf16x8 __attribute__((ext_vector_type(8)));
typedef float f32x4 __attribute__((ext_vector_type(4)));

static __device__ __forceinline__ unsigned short f2bf(float f) {
  __hip_bfloat16 b = __float2bfloat16(f);
  return *(unsigned short*)&b;
}
static __device__ __forceinline__ float bflo(unsigned int u) {
  return __uint_as_float(u << 16);
}
static __device__ __forceinline__ float bfhi(unsigned int u) {
  return __uint_as_float(u & 0xffff0000u);
}

// ---------------------------------------------------------------------------
// K0: pack weights into MFMA B-fragment order (blocks 0-39) + edge histogram
// (blocks 40+).
// ---------------------------------------------------------------------------
__global__ __launch_bounds__(256) void k_frag_hist(
    const float* __restrict__ enc_w, const float* __restrict__ M_w,
    const float* __restrict__ U_w,
    unsigned short* __restrict__ encf, unsigned short* __restrict__ Pf,
    unsigned short* __restrict__ Qf, unsigned short* __restrict__ Uf,
    const int* __restrict__ ei, int* __restrict__ cnt, int E) {
  const int b = blockIdx.x;
  if (b >= 40) {
    const int e = (b - 40) * 256 + threadIdx.x;
    if (e < E) atomicAdd(&cnt[ei[E + e]], 1);
    return;
  }
  const float* W; unsigned short* F; int KS; int lb;
  if (b < 8)       { W = enc_w + HD;     F = encf; KS = 4; lb = b; }
  else if (b < 16) { W = M_w;            F = Pf;   KS = 4; lb = b - 8; }
  else if (b < 24) { W = M_w + HD * HD;  F = Qf;   KS = 4; lb = b - 16; }
  else             { W = U_w;            F = Uf;   KS = 8; lb = b - 24; }
  const int gid = lb * 256 + threadIdx.x;
  const int lane = gid & 63;
  const int ks = (gid >> 6) % KS;
  const int tile = gid / (64 * KS);
  const int col = tile * 16 + (lane & 15);
  const int k0 = ks * 32 + (lane >> 4) * 8;
  unsigned short v[8];
#pragma unroll
  for (int j = 0; j < 8; ++j) v[j] = f2bf(W[(size_t)(k0 + j) * HD + col]);
  unsigned short* dst = F + ((size_t)(tile * KS + ks) * 64 + lane) * 8;
#pragma unroll
  for (int j = 0; j < 8; ++j) dst[j] = v[j];
}

// ---------------------------------------------------------------------------
// K_scan: single-block 1024-thread exclusive scan of counts (in `cursor`)
// -> row_ptr and cursor (prefix).  Replaces 3 dispatches (block-scan,
// partial-scan, add): at ~10us/dispatch overhead the fusion wins even on 1 CU.
// Thread t owns 49 contiguous elements; Hillis-Steele over 1024 partials.
// ---------------------------------------------------------------------------
__global__ __launch_bounds__(1024) void k_scan(
    int* __restrict__ cursor, int* __restrict__ row_ptr, int N) {
  __shared__ int s[1024];
  const int t = threadIdx.x;
  const int C = (N + 1023) >> 10;  // 49
  const int base = t * C;
  int sum = 0;
  for (int i = 0; i < C; ++i) {
    const int idx = base + i;
    if (idx < N) sum += cursor[idx];
  }
  s[t] = sum;
  __syncthreads();
  for (int off = 1; off < 1024; off <<= 1) {
    int xv = (t >= off) ? s[t - off] : 0;
    __syncthreads();
    if (t >= off) s[t] += xv;
    __syncthreads();
  }
  int run = s[t] - sum;  // exclusive prefix of this thread's chunk
  for (int i = 0; i < C; ++i) {
    const int idx = base + i;
    if (idx < N) {
      const int c = cursor[idx];  // read BEFORE overwrite (same buffer)
      row_ptr[idx] = run;
      cursor[idx] = run;
      run += c;
    }
  }
}

__global__ __launch_bounds__(256) void k_scatter(
    const int* __restrict__ ei, const float* __restrict__ edge_attr,
    int* __restrict__ cursor, int2* __restrict__ epack, int E) {
  const int e = blockIdx.x * 256 + threadIdx.x;
  if (e >= E) return;
  const int tgt = ei[E + e];
  const int pos = atomicAdd(&cursor[tgt], 1);
  epack[pos] = make_int2(ei[e], __float_as_int(edge_attr[e]));
}

// ---------------------------------------------------------------------------
// K1: MFMA encoder + P/Q.  16 nodes/block, 256 thr = 4 waves.
// ---------------------------------------------------------------------------
__global__ __launch_bounds__(256, 4) void k_enc_pq(
    const float* __restrict__ x, const float* __restrict__ pre_h,
    const float* __restrict__ enc_w, const float* __restrict__ enc_b,
    const float* __restrict__ M_b,
    const unsigned short* __restrict__ encf, const unsigned short* __restrict__ Pf,
    const unsigned short* __restrict__ Qf,
    unsigned short* __restrict__ zg, unsigned short* __restrict__ Pg,
    unsigned short* __restrict__ Qg) {
  __shared__ unsigned short phs[16 * APAD];  // pre_h bf16; later P staging
  __shared__ unsigned short zsh[16 * APAD];  // z bf16; later Q staging
  __shared__ float xs[16];
  const int t = threadIdx.x;
  const int n0 = blockIdx.x * 16;

  {
    const int r = t >> 4, c0 = (t & 15) * 8;
    const float4 a = *(const float4*)&pre_h[(size_t)(n0 + r) * HD + c0];
    const float4 b = *(const float4*)&pre_h[(size_t)(n0 + r) * HD + c0 + 4];
    unsigned short* d = &phs[r * APAD + c0];
    d[0] = f2bf(a.x); d[1] = f2bf(a.y); d[2] = f2bf(a.z); d[3] = f2bf(a.w);
    d[4] = f2bf(b.x); d[5] = f2bf(b.y); d[6] = f2bf(b.z); d[7] = f2bf(b.w);
  }
  if (t < 16) xs[t] = x[n0 + t];
  __syncthreads();

  const int w = t >> 6, l = t & 63;
  const int m = l & 15, q = l >> 4;

  // ---- encoder MFMA ----
  bf16x8 af[4];
#pragma unroll
  for (int ks = 0; ks < 4; ++ks)
    af[ks] = *(const bf16x8*)&phs[m * APAD + ks * 32 + q * 8];
  f32x4 acc[2] = {{0, 0, 0, 0}, {0, 0, 0, 0}};
#pragma unroll
  for (int tt = 0; tt < 2; ++tt) {
    const int tn = 2 * w + tt;
#pragma unroll
    for (int ks = 0; ks < 4; ++ks) {
      const bf16x8 bf = *(const bf16x8*)&encf[((size_t)(tn * 4 + ks) * 64 + l) * 8];
      acc[tt] = __builtin_amdgcn_mfma_f32_16x16x32_bf16(af[ks], bf, acc[tt], 0, 0, 0);
    }
  }
#pragma unroll
  for (int tt = 0; tt < 2; ++tt) {
    const int col = (2 * w + tt) * 16 + m;
    const float bb = enc_b[col];
    const float w0 = enc_w[col];  // row 0 (x feature)
#pragma unroll
    for (int r = 0; r < 4; ++r) {
      const int row = q * 4 + r;
      const float zv = fmaxf(acc[tt][r] + bb + xs[row] * w0, 0.0f);
      zsh[row * APAD + col] = f2bf(zv);
    }
  }
  __syncthreads();

  bf16x8 az[4];
#pragma unroll
  for (int ks = 0; ks < 4; ++ks)
    az[ks] = *(const bf16x8*)&zsh[m * APAD + ks * 32 + q * 8];
  {
    const int r = t >> 4, c0 = (t & 15) * 8;
    *(uint4*)&zg[(size_t)(n0 + r) * HD + c0] = *(const uint4*)&zsh[r * APAD + c0];
  }
  __syncthreads();

  // ---- P/Q MFMA ----
  f32x4 pacc[2] = {{0, 0, 0, 0}, {0, 0, 0, 0}};
  f32x4 qacc[2] = {{0, 0, 0, 0}, {0, 0, 0, 0}};
#pragma unroll
  for (int tt = 0; tt < 2; ++tt) {
    const int tn = 2 * w + tt;
#pragma unroll
    for (int ks = 0; ks < 4; ++ks) {
      const bf16x8 bp = *(const bf16x8*)&Pf[((size_t)(tn * 4 + ks) * 64 + l) * 8];
      const bf16x8 bq = *(const bf16x8*)&Qf[((size_t)(tn * 4 + ks) * 64 + l) * 8];
      pacc[tt] = __builtin_amdgcn_mfma_f32_16x16x32_bf16(az[ks], bp, pacc[tt], 0, 0, 0);
      qacc[tt] = __builtin_amdgcn_mfma_f32_16x16x32_bf16(az[ks], bq, qacc[tt], 0, 0, 0);
    }
  }
#pragma unroll
  for (int tt = 0; tt < 2; ++tt) {
    const int col = (2 * w + tt) * 16 + m;
    const float mb = M_b[col];
#pragma unroll
    for (int r = 0; r < 4; ++r) {
      const int row = q * 4 + r;
      phs[row * APAD + col] = f2bf(pacc[tt][r] + mb);  // P staging (bias folded)
      zsh[row * APAD + col] = f2bf(qacc[tt][r]);       // Q staging
    }
  }
  __syncthreads();
  {
    const int r = t >> 4, c0 = (t & 15) * 8;
    *(uint4*)&Pg[(size_t)(n0 + r) * HD + c0] = *(const uint4*)&phs[r * APAD + c0];
    *(uint4*)&Qg[(size_t)(n0 + r) * HD + c0] = *(const uint4*)&zsh[r * APAD + c0];
  }
}

// ---------------------------------------------------------------------------
// K2: fused gather-max + U-GEMM + decoder.  32 nodes/block, 4 waves.
// Gather: 16 lanes/edge direct from global (no LDS edge staging), result to
// ash in LDS (no ag round-trip).  hsum via per-block hpart (NO global
// atomics -- the round-2 56us stall).  Fusion is safe now that the atomic
// floor is gone: saves one dispatch (~10us) + 25.6 MB ag traffic.
// ---------------------------------------------------------------------------
__global__ __launch_bounds__(256, 6) void k_gu(
    const unsigned short* __restrict__ zg, const unsigned short* __restrict__ Pg,
    const unsigned short* __restrict__ Qg, const float* __restrict__ w_attr,
    const int* __restrict__ row_ptr, const int* __restrict__ row_end,
    const int2* __restrict__ epack, const unsigned short* __restrict__ Uf,
    const float* __restrict__ U_b, const float* __restrict__ dec_w,
    const float* __restrict__ dec_b,
    float* __restrict__ h_out, float* __restrict__ y_out,
    float* __restrict__ hpart, int N) {
  __shared__ unsigned short zsh[32 * APAD];
  __shared__ unsigned short ash[32 * APAD];
  __shared__ float hcol[HD];
  __shared__ float dacc[32];
  __shared__ float pr[32][8];
  const int t = threadIdx.x;
  const int n0 = blockIdx.x * 32;

  // stage z tile (clamped), zero accumulators
  {
    const int r = t >> 3, c0 = (t & 7) * 16;
    const int n = min(n0 + r, N - 1);
    *(uint4*)&zsh[r * APAD + c0]     = *(const uint4*)&zg[(size_t)n * HD + c0];
    *(uint4*)&zsh[r * APAD + c0 + 8] = *(const uint4*)&zg[(size_t)n * HD + c0 + 8];
  }
  if (t < 32) dacc[t] = 0.0f;
  if (t < HD) hcol[t] = 0.0f;

  const int w = t >> 6, l = t & 63;
  const int g = l >> 4, j = l & 15;

  // ---- gather-max: wave w, lane-group g -> nodes w*8+2g, w*8+2g+1 ----
  float wv[8];
  {
    const float4 wa = *(const float4*)&w_attr[j * 8];
    const float4 wb = *(const float4*)&w_attr[j * 8 + 4];
    wv[0] = wa.x; wv[1] = wa.y; wv[2] = wa.z; wv[3] = wa.w;
    wv[4] = wb.x; wv[5] = wb.y; wv[6] = wb.z; wv[7] = wb.w;
  }
#pragma unroll
  for (int i = 0; i < 2; ++i) {
    const int r = w * 8 + g * 2 + i;
    const int n = n0 + r;
    const int nc = min(n, N - 1);
    const int rs = row_ptr[nc], re = row_end[nc];
    float acc[8];
#pragma unroll
    for (int c = 0; c < 8; ++c) acc[c] = -INFINITY;
    for (int e = rs; e < re; e += 4) {
      int2 pk[4];
#pragma unroll
      for (int u = 0; u < 4; ++u) pk[u] = epack[min(e + u, re - 1)];
      uint4 qv[4];
#pragma unroll
      for (int u = 0; u < 4; ++u)
        qv[u] = *(const uint4*)&Qg[(size_t)pk[u].x * HD + j * 8];
#pragma unroll
      for (int u = 0; u < 4; ++u) {
        const float a = __int_as_float(pk[u].y);
        const unsigned int qq[4] = {qv[u].x, qv[u].y, qv[u].z, qv[u].w};
#pragma unroll
        for (int c = 0; c < 4; ++c) {
          acc[2 * c]     = fmaxf(acc[2 * c],     fmaf(a, wv[2 * c],     bflo(qq[c])));
          acc[2 * c + 1] = fmaxf(acc[2 * c + 1], fmaf(a, wv[2 * c + 1], bfhi(qq[c])));
        }
      }
    }
    float res[8];
    if (n < N && re > rs) {
      const uint4 pv = *(const uint4*)&Pg[(size_t)n * HD + j * 8];
      const unsigned int pp[4] = {pv.x, pv.y, pv.z, pv.w};
#pragma unroll
      for (int c = 0; c < 4; ++c) {
        res[2 * c]     = fmaxf(bflo(pp[c]) + acc[2 * c],     0.0f);
        res[2 * c + 1] = fmaxf(bfhi(pp[c]) + acc[2 * c + 1], 0.0f);
      }
    } else {
#pragma unroll
      for (int c = 0; c < 8; ++c) res[c] = 0.0f;
    }
    uint4 st;
    st.x = (unsigned)f2bf(res[0]) | ((unsigned)f2bf(res[1]) << 16);
    st.y = (unsigned)f2bf(res[2]) | ((unsigned)f2bf(res[3]) << 16);
    st.z = (unsigned)f2bf(res[4]) | ((unsigned)f2bf(res[5]) << 16);
    st.w = (unsigned)f2bf(res[6]) | ((unsigned)f2bf(res[7]) << 16);
    *(uint4*)&ash[r * APAD + j * 8] = st;
  }
  __syncthreads();

  // ---- U-GEMM: wave w -> M-tile (w&1), cols [64*(w>>1), +64) ----
  const int mt = w & 1, nh = w >> 1;
  const int m = mt * 16 + (l & 15), q = l >> 4;
  bf16x8 afz[4], afa[4];
#pragma unroll
  for (int ks = 0; ks < 4; ++ks) {
    afz[ks] = *(const bf16x8*)&zsh[m * APAD + ks * 32 + q * 8];
    afa[ks] = *(const bf16x8*)&ash[m * APAD + ks * 32 + q * 8];
  }
  f32x4 acc4[4] = {{0, 0, 0, 0}, {0, 0, 0, 0}, {0, 0, 0, 0}, {0, 0, 0, 0}};
#pragma unroll
  for (int tt = 0; tt < 4; ++tt) {
    const int tn = nh * 4 + tt;
#pragma unroll
    for (int ks = 0; ks < 8; ++ks) {
      const bf16x8 bf = *(const bf16x8*)&Uf[((size_t)(tn * 8 + ks) * 64 + l) * 8];
      const bf16x8 a = (ks < 4) ? afz[ks] : afa[ks - 4];
      acc4[tt] = __builtin_amdgcn_mfma_f32_16x16x32_bf16(a, bf, acc4[tt], 0, 0, 0);
    }
  }
  float dp[4] = {0.0f, 0.0f, 0.0f, 0.0f};
#pragma unroll
  for (int tt = 0; tt < 4; ++tt) {
    const int col = (nh * 4 + tt) * 16 + (l & 15);
    const float ub = U_b[col];
    const float dw = dec_w[HD + col];
    float s4 = 0.0f;
#pragma unroll
    for (int r = 0; r < 4; ++r) {
      const int rowl = mt * 16 + q * 4 + r;
      const int n = n0 + rowl;
      float hv = fmaxf(acc4[tt][r] + ub, 0.0f);
      if (n < N) h_out[(size_t)n * HD + col] = hv; else hv = 0.0f;
      s4 += hv;
      dp[r] += hv * dw;
    }
    atomicAdd(&hcol[col], s4);
  }
  // reduce decoder h-part across the 16 lanes sharing the same 4 rows
#pragma unroll
  for (int off = 1; off < 16; off <<= 1) {
#pragma unroll
    for (int r = 0; r < 4; ++r) dp[r] += __shfl_xor(dp[r], off);
  }
  if ((l & 15) == 0) {
#pragma unroll
    for (int r = 0; r < 4; ++r) atomicAdd(&dacc[mt * 16 + q * 4 + r], dp[r]);
  }

  // ---- decoder z-part: thread t -> node t>>3, cols (t&7)*16 .. +15 ----
  {
    const int r2 = t >> 3, s = t & 7;
    float part = 0.0f;
#pragma unroll
    for (int c = 0; c < 8; ++c) {
      const int kk = s * 16 + 2 * c;
      const unsigned int zu = *(const unsigned int*)&zsh[r2 * APAD + kk];
      part += bflo(zu) * dec_w[kk] + bfhi(zu) * dec_w[kk + 1];
    }
    pr[r2][s] = part;
  }
  __syncthreads();

  if (t < HD) hpart[(size_t)blockIdx.x * HD + t] = hcol[t];
  if (t < 32 && n0 + t < N) {
    float d = dec_b[0] + dacc[t];
#pragma unroll
    for (int s = 0; s < 8; ++s) d += pr[t][s];
    y_out[n0 + t] = 1.0f / (1.0f + expf(-d));
  }
}

// ---------------------------------------------------------------------------
// K3: fused hpart reduction + terminator.  1 block x 1024 thr.
// ter = (colsum(hpart)/N) . (ter_w[:H] + ter_w[H:]) + ter_b
// ---------------------------------------------------------------------------
__global__ __launch_bounds__(1024) void k_hredter(
    const float* __restrict__ hpart, const float* __restrict__ ter_w,
    const float* __restrict__ ter_b, float* __restrict__ out,
    float invN, int NB) {
  __shared__ float s[1024];
  const int t = threadIdx.x;
  const int col = t & (HD - 1);
  const int grp = t >> 7;  // 0..7
  float acc = 0.0f;
  for (int r = grp; r < NB; r += 8) acc += hpart[(size_t)r * HD + col];
  s[t] = acc;
  __syncthreads();
  if (t < 512) s[t] += s[t + 512];
  __syncthreads();
  if (t < 256) s[t] += s[t + 256];
  __syncthreads();
  float v = 0.0f;
  if (t < 128) {
    const float colsum = s[t] + s[t + 128];
    v = (colsum * invN) * (ter_w[t] + ter_w[HD + t]);
  }
#pragma unroll
  for (int o = 32; o > 0; o >>= 1) v += __shfl_down(v, o);
  __syncthreads();
  if (t < 128 && (t & 63) == 0) s[t >> 6] = v;
  __syncthreads();
  if (t == 0) out[0] = s[0] + s[1] + ter_b[0];
}

// ---------------------------------------------------------------------------
extern "C" void kernel_launch(void* const* d_in, const int* in_sizes, int n_in,
                              void* d_out, int out_size, void* d_ws, size_t ws_size,
                              hipStream_t stream) {
  const float* x        = (const float*)d_in[0];
  const float* pre_h    = (const float*)d_in[1];
  const float* edge_attr= (const float*)d_in[2];
  const float* enc_w    = (const float*)d_in[3];
  const float* enc_b    = (const float*)d_in[4];
  const float* M_w      = (const float*)d_in[5];
  const float* M_b      = (const float*)d_in[6];
  const float* U_w      = (const float*)d_in[7];
  const float* U_b      = (const float*)d_in[8];
  const float* dec_w    = (const float*)d_in[9];
  const float* dec_b    = (const float*)d_in[10];
  const float* ter_w    = (const float*)d_in[11];
  const float* ter_b    = (const float*)d_in[12];
  const int*   edge_idx = (const int*)d_in[13];

  const int N = in_sizes[0];      // 50000
  const int E = in_sizes[2];      // 600000
  const size_t NH = (size_t)N * HD;

  float* out = (float*)d_out;
  float* h_out = out;             // [0, N*H)
  float* y_out = out + NH;        // [N*H, N*H+N)
  float* ter_out = out + NH + N;

  // ws layout (bf16): zg | Pg | Qg | cursor(N) | row_ptr(N) | epack(E int2)
  //                   | encf | Pf | Qf | Uf | hpart
  unsigned short* zg = (unsigned short*)d_ws;
  unsigned short* Pg = zg + NH;
  unsigned short* Qg = Pg + NH;
  int*   cursor   = (int*)(Qg + NH);
  int*   row_ptr  = cursor + N;
  int2*  epack    = (int2*)(row_ptr + N);
  unsigned short* encf = (unsigned short*)(epack + E);
  unsigned short* Pf   = encf + 8 * 4 * 64 * 8;
  unsigned short* Qf   = Pf + 8 * 4 * 64 * 8;
  unsigned short* Uf   = Qf + 8 * 4 * 64 * 8;
  float* hpart = (float*)(Uf + 16 * 256 * 8);

  hipMemsetAsync(cursor, 0, (size_t)N * sizeof(int), stream);

  const int eb = (E + 255) / 256;             // 2344
  const int nb32 = (N + 31) / 32;             // 1563

  k_frag_hist<<<40 + eb, 256, 0, stream>>>(enc_w, M_w, U_w, encf, Pf, Qf, Uf,
                                           edge_idx, cursor, E);
  k_scan<<<1, 1024, 0, stream>>>(cursor, row_ptr, N);
  k_scatter<<<eb, 256, 0, stream>>>(edge_idx, edge_attr, cursor, epack, E);
  k_enc_pq<<<N / 16, 256, 0, stream>>>(x, pre_h, enc_w, enc_b, M_b,
                                       encf, Pf, Qf, zg, Pg, Qg);
  k_gu<<<nb32, 256, 0, stream>>>(
      zg, Pg, Qg, M_w + 256 * HD, row_ptr, cursor, epack, Uf,
      U_b, dec_w, dec_b, h_out, y_out, hpart, N);
  k_hredter<<<1, 1024, 0, stream>>>(hpart, ter_w, ter_b, ter_out,
                                    1.0f / (float)N, nb32);
}

// Round 5
// 284.756 us; speedup vs baseline: 1.4234x; 1.4234x over previous
//
#include <hip/hip_runtime.h>
#include <hip/hip_bf16.h>
#include <math.h>

// N=50000 nodes, E=600000 edges, H=128.
#define HD 128
#define APAD 136   // LDS row stride in ushorts (+8 pad: 272 B rows, 16B-aligned, 2-way bank alias = free)

typedef short bf16x8 __attribute__((ext_vector_type(8)));
typedef float f32x4 __attribute__((ext_vector_type(4)));

static __device__ __forceinline__ unsigned short f2bf(float f) {
  __hip_bfloat16 b = __float2bfloat16(f);
  return *(unsigned short*)&b;
}
static __device__ __forceinline__ float bflo(unsigned int u) {
  return __uint_as_float(u << 16);
}
static __device__ __forceinline__ float bfhi(unsigned int u) {
  return __uint_as_float(u & 0xffff0000u);
}

// ---------------------------------------------------------------------------
// K0: pack weights into MFMA B-fragment order (blocks 0-39) + edge histogram
// (blocks 40+).
// ---------------------------------------------------------------------------
__global__ __launch_bounds__(256) void k_frag_hist(
    const float* __restrict__ enc_w, const float* __restrict__ M_w,
    const float* __restrict__ U_w,
    unsigned short* __restrict__ encf, unsigned short* __restrict__ Pf,
    unsigned short* __restrict__ Qf, unsigned short* __restrict__ Uf,
    const int* __restrict__ ei, int* __restrict__ cnt, int E) {
  const int b = blockIdx.x;
  if (b >= 40) {
    const int e = (b - 40) * 256 + threadIdx.x;
    if (e < E) atomicAdd(&cnt[ei[E + e]], 1);
    return;
  }
  const float* W; unsigned short* F; int KS; int lb;
  if (b < 8)       { W = enc_w + HD;     F = encf; KS = 4; lb = b; }
  else if (b < 16) { W = M_w;            F = Pf;   KS = 4; lb = b - 8; }
  else if (b < 24) { W = M_w + HD * HD;  F = Qf;   KS = 4; lb = b - 16; }
  else             { W = U_w;            F = Uf;   KS = 8; lb = b - 24; }
  const int gid = lb * 256 + threadIdx.x;
  const int lane = gid & 63;
  const int ks = (gid >> 6) % KS;
  const int tile = gid / (64 * KS);
  const int col = tile * 16 + (lane & 15);
  const int k0 = ks * 32 + (lane >> 4) * 8;
  unsigned short v[8];
#pragma unroll
  for (int j = 0; j < 8; ++j) v[j] = f2bf(W[(size_t)(k0 + j) * HD + col]);
  unsigned short* dst = F + ((size_t)(tile * KS + ks) * 64 + lane) * 8;
#pragma unroll
  for (int j = 0; j < 8; ++j) dst[j] = v[j];
}

// ---------------------------------------------------------------------------
// CSR scan, multi-block (round-3 proven; round-4's 1-block fusion was a
// 128us latency-serialization disaster -- uncoalesced stride-49 loads on
// one CU).  k_scan_block: per-1024-chunk scan + block total to partials.
// ---------------------------------------------------------------------------
__global__ __launch_bounds__(256) void k_scan_block(
    const int* __restrict__ cnt, int* __restrict__ row_ptr,
    int* __restrict__ partials, int N) {
  __shared__ int s[256];
  const int t = threadIdx.x;
  const int base = blockIdx.x * 1024 + t * 4;
  int v[4], sum = 0;
#pragma unroll
  for (int i = 0; i < 4; ++i) {
    v[i] = (base + i < N) ? cnt[base + i] : 0;
    sum += v[i];
  }
  s[t] = sum;
  __syncthreads();
  for (int off = 1; off < 256; off <<= 1) {
    int xv = (t >= off) ? s[t - off] : 0;
    __syncthreads();
    if (t >= off) s[t] += xv;
    __syncthreads();
  }
  int run = s[t] - sum;
  if (t == 255) partials[blockIdx.x] = s[255];
#pragma unroll
  for (int i = 0; i < 4; ++i) {
    if (base + i < N) row_ptr[base + i] = run;
    run += v[i];
  }
}

// k_scan_add: wave 0 computes this block's partial offset from RAW block
// totals (parallel load + shuffle reduce, no serial chain) -- replaces the
// separate k_scan_partials dispatch.
__global__ __launch_bounds__(256) void k_scan_add(
    int* __restrict__ row_ptr, const int* __restrict__ partials,
    int* __restrict__ cursor, int N, int nb) {
  __shared__ int poff;
  const int t = threadIdx.x;
  if (t < 64) {
    int v = (t < nb && t < blockIdx.x) ? partials[t] : 0;
#pragma unroll
    for (int o = 32; o > 0; o >>= 1) v += __shfl_down(v, o);
    if (t == 0) poff = v;
  }
  __syncthreads();
  const int p = poff;
  const int base = blockIdx.x * 1024 + t * 4;
#pragma unroll
  for (int i = 0; i < 4; ++i) {
    if (base + i < N) {
      int v = row_ptr[base + i] + p;
      row_ptr[base + i] = v;
      cursor[base + i] = v;
    }
  }
}

// ---------------------------------------------------------------------------
// K1: merged scatter (blocks 0..eb-1) + MFMA encoder/P/Q (blocks eb..).
// Independent work: latency-bound scatter overlaps MFMA-bound encoder.
// ---------------------------------------------------------------------------
__global__ __launch_bounds__(256, 4) void k_scatter_enc(
    const int* __restrict__ ei, const float* __restrict__ edge_attr,
    int* __restrict__ cursor, int2* __restrict__ epack, int E, int eb,
    const float* __restrict__ x, const float* __restrict__ pre_h,
    const float* __restrict__ enc_w, const float* __restrict__ enc_b,
    const float* __restrict__ M_b,
    const unsigned short* __restrict__ encf, const unsigned short* __restrict__ Pf,
    const unsigned short* __restrict__ Qf,
    unsigned short* __restrict__ zg, unsigned short* __restrict__ Pg,
    unsigned short* __restrict__ Qg) {
  __shared__ unsigned short phs[16 * APAD];  // pre_h bf16; later P staging
  __shared__ unsigned short zsh[16 * APAD];  // z bf16; later Q staging
  __shared__ float xs[16];
  const int t = threadIdx.x;

  if (blockIdx.x < (unsigned)eb) {
    // ---- scatter path ----
    const int e = blockIdx.x * 256 + t;
    if (e < E) {
      const int tgt = ei[E + e];
      const int pos = atomicAdd(&cursor[tgt], 1);
      epack[pos] = make_int2(ei[e], __float_as_int(edge_attr[e]));
    }
    return;
  }

  // ---- encoder path ----
  const int n0 = (blockIdx.x - eb) * 16;
  {
    const int r = t >> 4, c0 = (t & 15) * 8;
    const float4 a = *(const float4*)&pre_h[(size_t)(n0 + r) * HD + c0];
    const float4 b = *(const float4*)&pre_h[(size_t)(n0 + r) * HD + c0 + 4];
    unsigned short* d = &phs[r * APAD + c0];
    d[0] = f2bf(a.x); d[1] = f2bf(a.y); d[2] = f2bf(a.z); d[3] = f2bf(a.w);
    d[4] = f2bf(b.x); d[5] = f2bf(b.y); d[6] = f2bf(b.z); d[7] = f2bf(b.w);
  }
  if (t < 16) xs[t] = x[n0 + t];
  __syncthreads();

  const int w = t >> 6, l = t & 63;
  const int m = l & 15, q = l >> 4;

  // ---- encoder MFMA ----
  bf16x8 af[4];
#pragma unroll
  for (int ks = 0; ks < 4; ++ks)
    af[ks] = *(const bf16x8*)&phs[m * APAD + ks * 32 + q * 8];
  f32x4 acc[2] = {{0, 0, 0, 0}, {0, 0, 0, 0}};
#pragma unroll
  for (int tt = 0; tt < 2; ++tt) {
    const int tn = 2 * w + tt;
#pragma unroll
    for (int ks = 0; ks < 4; ++ks) {
      const bf16x8 bf = *(const bf16x8*)&encf[((size_t)(tn * 4 + ks) * 64 + l) * 8];
      acc[tt] = __builtin_amdgcn_mfma_f32_16x16x32_bf16(af[ks], bf, acc[tt], 0, 0, 0);
    }
  }
#pragma unroll
  for (int tt = 0; tt < 2; ++tt) {
    const int col = (2 * w + tt) * 16 + m;
    const float bb = enc_b[col];
    const float w0 = enc_w[col];  // row 0 (x feature)
#pragma unroll
    for (int r = 0; r < 4; ++r) {
      const int row = q * 4 + r;
      const float zv = fmaxf(acc[tt][r] + bb + xs[row] * w0, 0.0f);
      zsh[row * APAD + col] = f2bf(zv);
    }
  }
  __syncthreads();

  bf16x8 az[4];
#pragma unroll
  for (int ks = 0; ks < 4; ++ks)
    az[ks] = *(const bf16x8*)&zsh[m * APAD + ks * 32 + q * 8];
  {
    const int r = t >> 4, c0 = (t & 15) * 8;
    *(uint4*)&zg[(size_t)(n0 + r) * HD + c0] = *(const uint4*)&zsh[r * APAD + c0];
  }
  __syncthreads();

  // ---- P/Q MFMA ----
  f32x4 pacc[2] = {{0, 0, 0, 0}, {0, 0, 0, 0}};
  f32x4 qacc[2] = {{0, 0, 0, 0}, {0, 0, 0, 0}};
#pragma unroll
  for (int tt = 0; tt < 2; ++tt) {
    const int tn = 2 * w + tt;
#pragma unroll
    for (int ks = 0; ks < 4; ++ks) {
      const bf16x8 bp = *(const bf16x8*)&Pf[((size_t)(tn * 4 + ks) * 64 + l) * 8];
      const bf16x8 bq = *(const bf16x8*)&Qf[((size_t)(tn * 4 + ks) * 64 + l) * 8];
      pacc[tt] = __builtin_amdgcn_mfma_f32_16x16x32_bf16(az[ks], bp, pacc[tt], 0, 0, 0);
      qacc[tt] = __builtin_amdgcn_mfma_f32_16x16x32_bf16(az[ks], bq, qacc[tt], 0, 0, 0);
    }
  }
#pragma unroll
  for (int tt = 0; tt < 2; ++tt) {
    const int col = (2 * w + tt) * 16 + m;
    const float mb = M_b[col];
#pragma unroll
    for (int r = 0; r < 4; ++r) {
      const int row = q * 4 + r;
      phs[row * APAD + col] = f2bf(pacc[tt][r] + mb);  // P staging (bias folded)
      zsh[row * APAD + col] = f2bf(qacc[tt][r]);       // Q staging
    }
  }
  __syncthreads();
  {
    const int r = t >> 4, c0 = (t & 15) * 8;
    *(uint4*)&Pg[(size_t)(n0 + r) * HD + c0] = *(const uint4*)&phs[r * APAD + c0];
    *(uint4*)&Qg[(size_t)(n0 + r) * HD + c0] = *(const uint4*)&zsh[r * APAD + c0];
  }
}

// ---------------------------------------------------------------------------
// K2a: edge gather-max -> ag.  NO LDS, NO barriers (round-3 proven: degree
// imbalance must not couple waves; round-4 re-fusion regressed).
// 16 lanes/edge, 4 lane-groups/wave, unroll-4 (tail clamped, max idempotent).
// ---------------------------------------------------------------------------
__global__ __launch_bounds__(256, 8) void k_gather(
    const unsigned short* __restrict__ Pg, const unsigned short* __restrict__ Qg,
    const float* __restrict__ w_attr,
    const int* __restrict__ row_ptr, const int* __restrict__ row_end,
    const int2* __restrict__ epack,
    unsigned short* __restrict__ ag, int N) {
  const int t = threadIdx.x;
  const int w = t >> 6, l = t & 63;
  const int g = l >> 4, j = l & 15;
  const int n0 = blockIdx.x * 32;

  float wv[8];
  {
    const float4 wa = *(const float4*)&w_attr[j * 8];
    const float4 wb = *(const float4*)&w_attr[j * 8 + 4];
    wv[0] = wa.x; wv[1] = wa.y; wv[2] = wa.z; wv[3] = wa.w;
    wv[4] = wb.x; wv[5] = wb.y; wv[6] = wb.z; wv[7] = wb.w;
  }

#pragma unroll
  for (int i = 0; i < 2; ++i) {
    const int r = w * 8 + g * 2 + i;
    const int n = n0 + r;
    const int nc = min(n, N - 1);
    const int rs = row_ptr[nc], re = row_end[nc];
    float acc[8];
#pragma unroll
    for (int c = 0; c < 8; ++c) acc[c] = -INFINITY;
    for (int e = rs; e < re; e += 4) {
      int2 pk[4];
#pragma unroll
      for (int u = 0; u < 4; ++u) pk[u] = epack[min(e + u, re - 1)];
      uint4 qv[4];
#pragma unroll
      for (int u = 0; u < 4; ++u)
        qv[u] = *(const uint4*)&Qg[(size_t)pk[u].x * HD + j * 8];
#pragma unroll
      for (int u = 0; u < 4; ++u) {
        const float a = __int_as_float(pk[u].y);
        const unsigned int qq[4] = {qv[u].x, qv[u].y, qv[u].z, qv[u].w};
#pragma unroll
        for (int c = 0; c < 4; ++c) {
          acc[2 * c]     = fmaxf(acc[2 * c],     fmaf(a, wv[2 * c],     bflo(qq[c])));
          acc[2 * c + 1] = fmaxf(acc[2 * c + 1], fmaf(a, wv[2 * c + 1], bfhi(qq[c])));
        }
      }
    }
    if (n < N) {
      float res[8];
      if (re > rs) {
        const uint4 pv = *(const uint4*)&Pg[(size_t)n * HD + j * 8];
        const unsigned int pp[4] = {pv.x, pv.y, pv.z, pv.w};
#pragma unroll
        for (int c = 0; c < 4; ++c) {
          res[2 * c]     = fmaxf(bflo(pp[c]) + acc[2 * c],     0.0f);
          res[2 * c + 1] = fmaxf(bfhi(pp[c]) + acc[2 * c + 1], 0.0f);
        }
      } else {
#pragma unroll
        for (int c = 0; c < 8; ++c) res[c] = 0.0f;
      }
      uint4 st;
      st.x = (unsigned)f2bf(res[0]) | ((unsigned)f2bf(res[1]) << 16);
      st.y = (unsigned)f2bf(res[2]) | ((unsigned)f2bf(res[3]) << 16);
      st.z = (unsigned)f2bf(res[4]) | ((unsigned)f2bf(res[5]) << 16);
      st.w = (unsigned)f2bf(res[6]) | ((unsigned)f2bf(res[7]) << 16);
      *(uint4*)&ag[(size_t)n * HD + j * 8] = st;
    }
  }
}

// ---------------------------------------------------------------------------
// K2b: dense U-GEMM (MFMA) + decoder + per-block h column partials
// (round-3 proven; NO global atomics).
// ---------------------------------------------------------------------------
__global__ __launch_bounds__(256, 8) void k_update(
    const unsigned short* __restrict__ zg, const unsigned short* __restrict__ ag,
    const unsigned short* __restrict__ Uf,
    const float* __restrict__ U_b, const float* __restrict__ dec_w,
    const float* __restrict__ dec_b,
    float* __restrict__ h_out, float* __restrict__ y_out,
    float* __restrict__ hpart, int N) {
  __shared__ unsigned short zsh[32 * APAD];
  __shared__ unsigned short ash[32 * APAD];
  __shared__ float hcol[HD];
  __shared__ float dacc[32];
  __shared__ float pr[32][8];
  const int t = threadIdx.x;
  const int n0 = blockIdx.x * 32;

  {
    const int r = t >> 3, c0 = (t & 7) * 16;
    const int n = min(n0 + r, N - 1);
    *(uint4*)&zsh[r * APAD + c0]     = *(const uint4*)&zg[(size_t)n * HD + c0];
    *(uint4*)&zsh[r * APAD + c0 + 8] = *(const uint4*)&zg[(size_t)n * HD + c0 + 8];
    *(uint4*)&ash[r * APAD + c0]     = *(const uint4*)&ag[(size_t)n * HD + c0];
    *(uint4*)&ash[r * APAD + c0 + 8] = *(const uint4*)&ag[(size_t)n * HD + c0 + 8];
  }
  if (t < 32) dacc[t] = 0.0f;
  if (t < HD) hcol[t] = 0.0f;
  __syncthreads();

  const int w = t >> 6, l = t & 63;

  // ---- U-GEMM: wave w -> M-tile (w&1), cols [64*(w>>1), +64) ----
  const int mt = w & 1, nh = w >> 1;
  const int m = mt * 16 + (l & 15), q = l >> 4;
  bf16x8 afz[4], afa[4];
#pragma unroll
  for (int ks = 0; ks < 4; ++ks) {
    afz[ks] = *(const bf16x8*)&zsh[m * APAD + ks * 32 + q * 8];
    afa[ks] = *(const bf16x8*)&ash[m * APAD + ks * 32 + q * 8];
  }
  f32x4 acc4[4] = {{0, 0, 0, 0}, {0, 0, 0, 0}, {0, 0, 0, 0}, {0, 0, 0, 0}};
#pragma unroll
  for (int tt = 0; tt < 4; ++tt) {
    const int tn = nh * 4 + tt;
#pragma unroll
    for (int ks = 0; ks < 8; ++ks) {
      const bf16x8 bf = *(const bf16x8*)&Uf[((size_t)(tn * 8 + ks) * 64 + l) * 8];
      const bf16x8 a = (ks < 4) ? afz[ks] : afa[ks - 4];
      acc4[tt] = __builtin_amdgcn_mfma_f32_16x16x32_bf16(a, bf, acc4[tt], 0, 0, 0);
    }
  }
  float dp[4] = {0.0f, 0.0f, 0.0f, 0.0f};
#pragma unroll
  for (int tt = 0; tt < 4; ++tt) {
    const int col = (nh * 4 + tt) * 16 + (l & 15);
    const float ub = U_b[col];
    const float dw = dec_w[HD + col];
    float s4 = 0.0f;
#pragma unroll
    for (int r = 0; r < 4; ++r) {
      const int rowl = mt * 16 + q * 4 + r;
      const int n = n0 + rowl;
      float hv = fmaxf(acc4[tt][r] + ub, 0.0f);
      if (n < N) h_out[(size_t)n * HD + col] = hv; else hv = 0.0f;
      s4 += hv;
      dp[r] += hv * dw;
    }
    atomicAdd(&hcol[col], s4);
  }
  // reduce decoder h-part across the 16 lanes sharing the same 4 rows
#pragma unroll
  for (int off = 1; off < 16; off <<= 1) {
#pragma unroll
    for (int r = 0; r < 4; ++r) dp[r] += __shfl_xor(dp[r], off);
  }
  if ((l & 15) == 0) {
#pragma unroll
    for (int r = 0; r < 4; ++r) atomicAdd(&dacc[mt * 16 + q * 4 + r], dp[r]);
  }

  // ---- decoder z-part: thread t -> node t>>3, cols (t&7)*16 .. +15 ----
  {
    const int r2 = t >> 3, s = t & 7;
    float part = 0.0f;
#pragma unroll
    for (int c = 0; c < 8; ++c) {
      const int kk = s * 16 + 2 * c;
      const unsigned int zu = *(const unsigned int*)&zsh[r2 * APAD + kk];
      const unsigned int hu = *(const unsigned int*)&ash[r2 * APAD + kk];
      part += bflo(zu) * dec_w[kk] + bfhi(zu) * dec_w[kk + 1];
    }
    pr[r2][s] = part;
  }
  __syncthreads();

  if (t < HD) hpart[(size_t)blockIdx.x * HD + t] = hcol[t];
  if (t < 32 && n0 + t < N) {
    float d = dec_b[0] + dacc[t];
#pragma unroll
    for (int s = 0; s < 8; ++s) d += pr[t][s];
    y_out[n0 + t] = 1.0f / (1.0f + expf(-d));
  }
}

// ---------------------------------------------------------------------------
// K3: fused hpart reduction + terminator.  1 block x 1024 thr.
// ter = (colsum(hpart)/N) . (ter_w[:H] + ter_w[H:]) + ter_b
// ---------------------------------------------------------------------------
__global__ __launch_bounds__(1024) void k_hredter(
    const float* __restrict__ hpart, const float* __restrict__ ter_w,
    const float* __restrict__ ter_b, float* __restrict__ out,
    float invN, int NB) {
  __shared__ float s[1024];
  const int t = threadIdx.x;
  const int col = t & (HD - 1);
  const int grp = t >> 7;  // 0..7
  float acc = 0.0f;
  for (int r = grp; r < NB; r += 8) acc += hpart[(size_t)r * HD + col];
  s[t] = acc;
  __syncthreads();
  if (t < 512) s[t] += s[t + 512];
  __syncthreads();
  if (t < 256) s[t] += s[t + 256];
  __syncthreads();
  float v = 0.0f;
  if (t < 128) {
    const float colsum = s[t] + s[t + 128];
    v = (colsum * invN) * (ter_w[t] + ter_w[HD + t]);
  }
#pragma unroll
  for (int o = 32; o > 0; o >>= 1) v += __shfl_down(v, o);
  __syncthreads();
  if (t < 128 && (t & 63) == 0) s[t >> 6] = v;
  __syncthreads();
  if (t == 0) out[0] = s[0] + s[1] + ter_b[0];
}

// ---------------------------------------------------------------------------
extern "C" void kernel_launch(void* const* d_in, const int* in_sizes, int n_in,
                              void* d_out, int out_size, void* d_ws, size_t ws_size,
                              hipStream_t stream) {
  const float* x        = (const float*)d_in[0];
  const float* pre_h    = (const float*)d_in[1];
  const float* edge_attr= (const float*)d_in[2];
  const float* enc_w    = (const float*)d_in[3];
  const float* enc_b    = (const float*)d_in[4];
  const float* M_w      = (const float*)d_in[5];
  const float* M_b      = (const float*)d_in[6];
  const float* U_w      = (const float*)d_in[7];
  const float* U_b      = (const float*)d_in[8];
  const float* dec_w    = (const float*)d_in[9];
  const float* dec_b    = (const float*)d_in[10];
  const float* ter_w    = (const float*)d_in[11];
  const float* ter_b    = (const float*)d_in[12];
  const int*   edge_idx = (const int*)d_in[13];

  const int N = in_sizes[0];      // 50000
  const int E = in_sizes[2];      // 600000
  const size_t NH = (size_t)N * HD;

  float* out = (float*)d_out;
  float* h_out = out;             // [0, N*H)
  float* y_out = out + NH;        // [N*H, N*H+N)
  float* ter_out = out + NH + N;

  // ws layout (bf16): zg | Pg | Qg | ag | cursor(N) | row_ptr(N) | partials(64)
  //                   | epack(E int2) | encf | Pf | Qf | Uf | hpart
  unsigned short* zg = (unsigned short*)d_ws;
  unsigned short* Pg = zg + NH;
  unsigned short* Qg = Pg + NH;
  unsigned short* ag = Qg + NH;
  int*   cursor   = (int*)(ag + NH);
  int*   row_ptr  = cursor + N;
  int*   partials = row_ptr + N;
  int2*  epack    = (int2*)(partials + 64);
  unsigned short* encf = (unsigned short*)(epack + E);
  unsigned short* Pf   = encf + 8 * 4 * 64 * 8;
  unsigned short* Qf   = Pf + 8 * 4 * 64 * 8;
  unsigned short* Uf   = Qf + 8 * 4 * 64 * 8;
  float* hpart = (float*)(Uf + 16 * 256 * 8);

  hipMemsetAsync(cursor, 0, (size_t)N * sizeof(int), stream);

  const int scan_blocks = (N + 1023) / 1024;  // 49
  const int eb = (E + 255) / 256;             // 2344
  const int nb32 = (N + 31) / 32;             // 1563

  k_frag_hist<<<40 + eb, 256, 0, stream>>>(enc_w, M_w, U_w, encf, Pf, Qf, Uf,
                                           edge_idx, cursor, E);
  k_scan_block<<<scan_blocks, 256, 0, stream>>>(cursor, row_ptr, partials, N);
  k_scan_add<<<scan_blocks, 256, 0, stream>>>(row_ptr, partials, cursor, N,
                                              scan_blocks);
  k_scatter_enc<<<eb + N / 16, 256, 0, stream>>>(
      edge_idx, edge_attr, cursor, epack, E, eb,
      x, pre_h, enc_w, enc_b, M_b, encf, Pf, Qf, zg, Pg, Qg);
  k_gather<<<nb32, 256, 0, stream>>>(
      Pg, Qg, M_w + 256 * HD, row_ptr, cursor, epack, ag, N);
  k_update<<<nb32, 256, 0, stream>>>(
      zg, ag, Uf, U_b, dec_w, dec_b, h_out, y_out, hpart, N);
  k_hredter<<<1, 1024, 0, stream>>>(hpart, ter_w, ter_b, ter_out,
                                    1.0f / (float)N, nb32);
}

// Round 6
// 238.158 us; speedup vs baseline: 1.7019x; 1.1957x over previous
//
#include <hip/hip_runtime.h>
#include <hip/hip_bf16.h>
#include <math.h>

// N=50000 nodes, E=600000 edges, H=128.
#define HD 128
#define APAD 136   // LDS row stride in ushorts (+8 pad: 272 B rows, 16B-aligned, 2-way bank alias = free)

typedef short bf16x8 __attribute__((ext_vector_type(8)));
typedef float f32x4 __attribute__((ext_vector_type(4)));

static __device__ __forceinline__ unsigned short f2bf(float f) {
  __hip_bfloat16 b = __float2bfloat16(f);
  return *(unsigned short*)&b;
}
static __device__ __forceinline__ float bflo(unsigned int u) {
  return __uint_as_float(u << 16);
}
static __device__ __forceinline__ float bfhi(unsigned int u) {
  return __uint_as_float(u & 0xffff0000u);
}

// ---------------------------------------------------------------------------
// K0: pack weights into MFMA B-fragment order (blocks 0-39) + edge histogram
// (blocks 40+).
// ---------------------------------------------------------------------------
__global__ __launch_bounds__(256) void k_frag_hist(
    const float* __restrict__ enc_w, const float* __restrict__ M_w,
    const float* __restrict__ U_w,
    unsigned short* __restrict__ encf, unsigned short* __restrict__ Pf,
    unsigned short* __restrict__ Qf, unsigned short* __restrict__ Uf,
    const int* __restrict__ ei, int* __restrict__ cnt, int E) {
  const int b = blockIdx.x;
  if (b >= 40) {
    const int e = (b - 40) * 256 + threadIdx.x;
    if (e < E) atomicAdd(&cnt[ei[E + e]], 1);
    return;
  }
  const float* W; unsigned short* F; int KS; int lb;
  if (b < 8)       { W = enc_w + HD;     F = encf; KS = 4; lb = b; }
  else if (b < 16) { W = M_w;            F = Pf;   KS = 4; lb = b - 8; }
  else if (b < 24) { W = M_w + HD * HD;  F = Qf;   KS = 4; lb = b - 16; }
  else             { W = U_w;            F = Uf;   KS = 8; lb = b - 24; }
  const int gid = lb * 256 + threadIdx.x;
  const int lane = gid & 63;
  const int ks = (gid >> 6) % KS;
  const int tile = gid / (64 * KS);
  const int col = tile * 16 + (lane & 15);
  const int k0 = ks * 32 + (lane >> 4) * 8;
  unsigned short v[8];
#pragma unroll
  for (int j = 0; j < 8; ++j) v[j] = f2bf(W[(size_t)(k0 + j) * HD + col]);
  unsigned short* dst = F + ((size_t)(tile * KS + ks) * 64 + lane) * 8;
#pragma unroll
  for (int j = 0; j < 8; ++j) dst[j] = v[j];
}

// ---------------------------------------------------------------------------
// CSR scan, multi-block (round-3 proven).  k_scan_block also zeroes hsum
// (block 0) so no extra memset dispatch is needed.
// ---------------------------------------------------------------------------
__global__ __launch_bounds__(256) void k_scan_block(
    const int* __restrict__ cnt, int* __restrict__ row_ptr,
    int* __restrict__ partials, float* __restrict__ hsum, int N) {
  __shared__ int s[256];
  const int t = threadIdx.x;
  if (blockIdx.x == 0 && t < HD) hsum[t] = 0.0f;
  const int base = blockIdx.x * 1024 + t * 4;
  int v[4], sum = 0;
#pragma unroll
  for (int i = 0; i < 4; ++i) {
    v[i] = (base + i < N) ? cnt[base + i] : 0;
    sum += v[i];
  }
  s[t] = sum;
  __syncthreads();
  for (int off = 1; off < 256; off <<= 1) {
    int xv = (t >= off) ? s[t - off] : 0;
    __syncthreads();
    if (t >= off) s[t] += xv;
    __syncthreads();
  }
  int run = s[t] - sum;
  if (t == 255) partials[blockIdx.x] = s[255];
#pragma unroll
  for (int i = 0; i < 4; ++i) {
    if (base + i < N) row_ptr[base + i] = run;
    run += v[i];
  }
}

// k_scan_add: wave 0 computes this block's partial offset from RAW block
// totals (parallel load + shuffle reduce, no serial chain).
__global__ __launch_bounds__(256) void k_scan_add(
    int* __restrict__ row_ptr, const int* __restrict__ partials,
    int* __restrict__ cursor, int N, int nb) {
  __shared__ int poff;
  const int t = threadIdx.x;
  if (t < 64) {
    int v = (t < nb && t < blockIdx.x) ? partials[t] : 0;
#pragma unroll
    for (int o = 32; o > 0; o >>= 1) v += __shfl_down(v, o);
    if (t == 0) poff = v;
  }
  __syncthreads();
  const int p = poff;
  const int base = blockIdx.x * 1024 + t * 4;
#pragma unroll
  for (int i = 0; i < 4; ++i) {
    if (base + i < N) {
      int v = row_ptr[base + i] + p;
      row_ptr[base + i] = v;
      cursor[base + i] = v;
    }
  }
}

// ---------------------------------------------------------------------------
// K1: merged scatter (blocks 0..eb-1) + MFMA encoder/P/Q (blocks eb..).
// Independent work: latency-bound scatter overlaps MFMA-bound encoder
// (round-5 measured: merged 57us < separate sum).
// ---------------------------------------------------------------------------
__global__ __launch_bounds__(256, 4) void k_scatter_enc(
    const int* __restrict__ ei, const float* __restrict__ edge_attr,
    int* __restrict__ cursor, int2* __restrict__ epack, int E, int eb,
    const float* __restrict__ x, const float* __restrict__ pre_h,
    const float* __restrict__ enc_w, const float* __restrict__ enc_b,
    const float* __restrict__ M_b,
    const unsigned short* __restrict__ encf, const unsigned short* __restrict__ Pf,
    const unsigned short* __restrict__ Qf,
    unsigned short* __restrict__ zg, unsigned short* __restrict__ Pg,
    unsigned short* __restrict__ Qg) {
  __shared__ unsigned short phs[16 * APAD];  // pre_h bf16; later P staging
  __shared__ unsigned short zsh[16 * APAD];  // z bf16; later Q staging
  __shared__ float xs[16];
  const int t = threadIdx.x;

  if (blockIdx.x < (unsigned)eb) {
    // ---- scatter path ----
    const int e = blockIdx.x * 256 + t;
    if (e < E) {
      const int tgt = ei[E + e];
      const int pos = atomicAdd(&cursor[tgt], 1);
      epack[pos] = make_int2(ei[e], __float_as_int(edge_attr[e]));
    }
    return;
  }

  // ---- encoder path ----
  const int n0 = (blockIdx.x - eb) * 16;
  {
    const int r = t >> 4, c0 = (t & 15) * 8;
    const float4 a = *(const float4*)&pre_h[(size_t)(n0 + r) * HD + c0];
    const float4 b = *(const float4*)&pre_h[(size_t)(n0 + r) * HD + c0 + 4];
    unsigned short* d = &phs[r * APAD + c0];
    d[0] = f2bf(a.x); d[1] = f2bf(a.y); d[2] = f2bf(a.z); d[3] = f2bf(a.w);
    d[4] = f2bf(b.x); d[5] = f2bf(b.y); d[6] = f2bf(b.z); d[7] = f2bf(b.w);
  }
  if (t < 16) xs[t] = x[n0 + t];
  __syncthreads();

  const int w = t >> 6, l = t & 63;
  const int m = l & 15, q = l >> 4;

  // ---- encoder MFMA ----
  bf16x8 af[4];
#pragma unroll
  for (int ks = 0; ks < 4; ++ks)
    af[ks] = *(const bf16x8*)&phs[m * APAD + ks * 32 + q * 8];
  f32x4 acc[2] = {{0, 0, 0, 0}, {0, 0, 0, 0}};
#pragma unroll
  for (int tt = 0; tt < 2; ++tt) {
    const int tn = 2 * w + tt;
#pragma unroll
    for (int ks = 0; ks < 4; ++ks) {
      const bf16x8 bf = *(const bf16x8*)&encf[((size_t)(tn * 4 + ks) * 64 + l) * 8];
      acc[tt] = __builtin_amdgcn_mfma_f32_16x16x32_bf16(af[ks], bf, acc[tt], 0, 0, 0);
    }
  }
#pragma unroll
  for (int tt = 0; tt < 2; ++tt) {
    const int col = (2 * w + tt) * 16 + m;
    const float bb = enc_b[col];
    const float w0 = enc_w[col];  // row 0 (x feature)
#pragma unroll
    for (int r = 0; r < 4; ++r) {
      const int row = q * 4 + r;
      const float zv = fmaxf(acc[tt][r] + bb + xs[row] * w0, 0.0f);
      zsh[row * APAD + col] = f2bf(zv);
    }
  }
  __syncthreads();

  bf16x8 az[4];
#pragma unroll
  for (int ks = 0; ks < 4; ++ks)
    az[ks] = *(const bf16x8*)&zsh[m * APAD + ks * 32 + q * 8];
  {
    const int r = t >> 4, c0 = (t & 15) * 8;
    *(uint4*)&zg[(size_t)(n0 + r) * HD + c0] = *(const uint4*)&zsh[r * APAD + c0];
  }
  __syncthreads();

  // ---- P/Q MFMA ----
  f32x4 pacc[2] = {{0, 0, 0, 0}, {0, 0, 0, 0}};
  f32x4 qacc[2] = {{0, 0, 0, 0}, {0, 0, 0, 0}};
#pragma unroll
  for (int tt = 0; tt < 2; ++tt) {
    const int tn = 2 * w + tt;
#pragma unroll
    for (int ks = 0; ks < 4; ++ks) {
      const bf16x8 bp = *(const bf16x8*)&Pf[((size_t)(tn * 4 + ks) * 64 + l) * 8];
      const bf16x8 bq = *(const bf16x8*)&Qf[((size_t)(tn * 4 + ks) * 64 + l) * 8];
      pacc[tt] = __builtin_amdgcn_mfma_f32_16x16x32_bf16(az[ks], bp, pacc[tt], 0, 0, 0);
      qacc[tt] = __builtin_amdgcn_mfma_f32_16x16x32_bf16(az[ks], bq, qacc[tt], 0, 0, 0);
    }
  }
#pragma unroll
  for (int tt = 0; tt < 2; ++tt) {
    const int col = (2 * w + tt) * 16 + m;
    const float mb = M_b[col];
#pragma unroll
    for (int r = 0; r < 4; ++r) {
      const int row = q * 4 + r;
      phs[row * APAD + col] = f2bf(pacc[tt][r] + mb);  // P staging (bias folded)
      zsh[row * APAD + col] = f2bf(qacc[tt][r]);       // Q staging
    }
  }
  __syncthreads();
  {
    const int r = t >> 4, c0 = (t & 15) * 8;
    *(uint4*)&Pg[(size_t)(n0 + r) * HD + c0] = *(const uint4*)&phs[r * APAD + c0];
    *(uint4*)&Qg[(size_t)(n0 + r) * HD + c0] = *(const uint4*)&zsh[r * APAD + c0];
  }
}

// ---------------------------------------------------------------------------
// K2a: edge gather-max -> ag.  NO LDS, NO barriers (round-3 proven: degree
// imbalance must not couple waves).  16 lanes/edge, 4 lane-groups/wave,
// unroll-4 (tail clamped, max idempotent).
// ---------------------------------------------------------------------------
__global__ __launch_bounds__(256, 8) void k_gather(
    const unsigned short* __restrict__ Pg, const unsigned short* __restrict__ Qg,
    const float* __restrict__ w_attr,
    const int* __restrict__ row_ptr, const int* __restrict__ row_end,
    const int2* __restrict__ epack,
    unsigned short* __restrict__ ag, int N) {
  const int t = threadIdx.x;
  const int w = t >> 6, l = t & 63;
  const int g = l >> 4, j = l & 15;
  const int n0 = blockIdx.x * 32;

  float wv[8];
  {
    const float4 wa = *(const float4*)&w_attr[j * 8];
    const float4 wb = *(const float4*)&w_attr[j * 8 + 4];
    wv[0] = wa.x; wv[1] = wa.y; wv[2] = wa.z; wv[3] = wa.w;
    wv[4] = wb.x; wv[5] = wb.y; wv[6] = wb.z; wv[7] = wb.w;
  }

#pragma unroll
  for (int i = 0; i < 2; ++i) {
    const int r = w * 8 + g * 2 + i;
    const int n = n0 + r;
    const int nc = min(n, N - 1);
    const int rs = row_ptr[nc], re = row_end[nc];
    float acc[8];
#pragma unroll
    for (int c = 0; c < 8; ++c) acc[c] = -INFINITY;
    for (int e = rs; e < re; e += 4) {
      int2 pk[4];
#pragma unroll
      for (int u = 0; u < 4; ++u) pk[u] = epack[min(e + u, re - 1)];
      uint4 qv[4];
#pragma unroll
      for (int u = 0; u < 4; ++u)
        qv[u] = *(const uint4*)&Qg[(size_t)pk[u].x * HD + j * 8];
#pragma unroll
      for (int u = 0; u < 4; ++u) {
        const float a = __int_as_float(pk[u].y);
        const unsigned int qq[4] = {qv[u].x, qv[u].y, qv[u].z, qv[u].w};
#pragma unroll
        for (int c = 0; c < 4; ++c) {
          acc[2 * c]     = fmaxf(acc[2 * c],     fmaf(a, wv[2 * c],     bflo(qq[c])));
          acc[2 * c + 1] = fmaxf(acc[2 * c + 1], fmaf(a, wv[2 * c + 1], bfhi(qq[c])));
        }
      }
    }
    if (n < N) {
      float res[8];
      if (re > rs) {
        const uint4 pv = *(const uint4*)&Pg[(size_t)n * HD + j * 8];
        const unsigned int pp[4] = {pv.x, pv.y, pv.z, pv.w};
#pragma unroll
        for (int c = 0; c < 4; ++c) {
          res[2 * c]     = fmaxf(bflo(pp[c]) + acc[2 * c],     0.0f);
          res[2 * c + 1] = fmaxf(bfhi(pp[c]) + acc[2 * c + 1], 0.0f);
        }
      } else {
#pragma unroll
        for (int c = 0; c < 8; ++c) res[c] = 0.0f;
      }
      uint4 st;
      st.x = (unsigned)f2bf(res[0]) | ((unsigned)f2bf(res[1]) << 16);
      st.y = (unsigned)f2bf(res[2]) | ((unsigned)f2bf(res[3]) << 16);
      st.z = (unsigned)f2bf(res[4]) | ((unsigned)f2bf(res[5]) << 16);
      st.w = (unsigned)f2bf(res[6]) | ((unsigned)f2bf(res[7]) << 16);
      *(uint4*)&ag[(size_t)n * HD + j * 8] = st;
    }
  }
}

// ---------------------------------------------------------------------------
// K2b: dense U-GEMM (MFMA) + decoder + per-block h column partials
// (round-3 proven; NO global atomics).
// ---------------------------------------------------------------------------
__global__ __launch_bounds__(256, 8) void k_update(
    const unsigned short* __restrict__ zg, const unsigned short* __restrict__ ag,
    const unsigned short* __restrict__ Uf,
    const float* __restrict__ U_b, const float* __restrict__ dec_w,
    const float* __restrict__ dec_b,
    float* __restrict__ h_out, float* __restrict__ y_out,
    float* __restrict__ hpart, int N) {
  __shared__ unsigned short zsh[32 * APAD];
  __shared__ unsigned short ash[32 * APAD];
  __shared__ float hcol[HD];
  __shared__ float dacc[32];
  __shared__ float pr[32][8];
  const int t = threadIdx.x;
  const int n0 = blockIdx.x * 32;

  {
    const int r = t >> 3, c0 = (t & 7) * 16;
    const int n = min(n0 + r, N - 1);
    *(uint4*)&zsh[r * APAD + c0]     = *(const uint4*)&zg[(size_t)n * HD + c0];
    *(uint4*)&zsh[r * APAD + c0 + 8] = *(const uint4*)&zg[(size_t)n * HD + c0 + 8];
    *(uint4*)&ash[r * APAD + c0]     = *(const uint4*)&ag[(size_t)n * HD + c0];
    *(uint4*)&ash[r * APAD + c0 + 8] = *(const uint4*)&ag[(size_t)n * HD + c0 + 8];
  }
  if (t < 32) dacc[t] = 0.0f;
  if (t < HD) hcol[t] = 0.0f;
  __syncthreads();

  const int w = t >> 6, l = t & 63;

  // ---- U-GEMM: wave w -> M-tile (w&1), cols [64*(w>>1), +64) ----
  const int mt = w & 1, nh = w >> 1;
  const int m = mt * 16 + (l & 15), q = l >> 4;
  bf16x8 afz[4], afa[4];
#pragma unroll
  for (int ks = 0; ks < 4; ++ks) {
    afz[ks] = *(const bf16x8*)&zsh[m * APAD + ks * 32 + q * 8];
    afa[ks] = *(const bf16x8*)&ash[m * APAD + ks * 32 + q * 8];
  }
  f32x4 acc4[4] = {{0, 0, 0, 0}, {0, 0, 0, 0}, {0, 0, 0, 0}, {0, 0, 0, 0}};
#pragma unroll
  for (int tt = 0; tt < 4; ++tt) {
    const int tn = nh * 4 + tt;
#pragma unroll
    for (int ks = 0; ks < 8; ++ks) {
      const bf16x8 bf = *(const bf16x8*)&Uf[((size_t)(tn * 8 + ks) * 64 + l) * 8];
      const bf16x8 a = (ks < 4) ? afz[ks] : afa[ks - 4];
      acc4[tt] = __builtin_amdgcn_mfma_f32_16x16x32_bf16(a, bf, acc4[tt], 0, 0, 0);
    }
  }
  float dp[4] = {0.0f, 0.0f, 0.0f, 0.0f};
#pragma unroll
  for (int tt = 0; tt < 4; ++tt) {
    const int col = (nh * 4 + tt) * 16 + (l & 15);
    const float ub = U_b[col];
    const float dw = dec_w[HD + col];
    float s4 = 0.0f;
#pragma unroll
    for (int r = 0; r < 4; ++r) {
      const int rowl = mt * 16 + q * 4 + r;
      const int n = n0 + rowl;
      float hv = fmaxf(acc4[tt][r] + ub, 0.0f);
      if (n < N) h_out[(size_t)n * HD + col] = hv; else hv = 0.0f;
      s4 += hv;
      dp[r] += hv * dw;
    }
    atomicAdd(&hcol[col], s4);
  }
  // reduce decoder h-part across the 16 lanes sharing the same 4 rows
#pragma unroll
  for (int off = 1; off < 16; off <<= 1) {
#pragma unroll
    for (int r = 0; r < 4; ++r) dp[r] += __shfl_xor(dp[r], off);
  }
  if ((l & 15) == 0) {
#pragma unroll
    for (int r = 0; r < 4; ++r) atomicAdd(&dacc[mt * 16 + q * 4 + r], dp[r]);
  }

  // ---- decoder z-part: thread t -> node t>>3, cols (t&7)*16 .. +15 ----
  {
    const int r2 = t >> 3, s = t & 7;
    float part = 0.0f;
#pragma unroll
    for (int c = 0; c < 8; ++c) {
      const int kk = s * 16 + 2 * c;
      const unsigned int zu = *(const unsigned int*)&zsh[r2 * APAD + kk];
      part += bflo(zu) * dec_w[kk] + bfhi(zu) * dec_w[kk + 1];
    }
    pr[r2][s] = part;
  }
  __syncthreads();

  if (t < HD) hpart[(size_t)blockIdx.x * HD + t] = hcol[t];
  if (t < 32 && n0 + t < N) {
    float d = dec_b[0] + dacc[t];
#pragma unroll
    for (int s = 0; s < 8; ++s) d += pr[t][s];
    y_out[n0 + t] = 1.0f / (1.0f + expf(-d));
  }
}

// ---------------------------------------------------------------------------
// K2c: parallel reduce hpart[NB][128] -> hsum[128].  64 blocks x 256 thr,
// grid-stride coalesced; 8K total atomics on 128 addresses (harmless).
// (Round-5's 1-block fused version was 53.6us: single-CU BW-bound.)
// ---------------------------------------------------------------------------
__global__ __launch_bounds__(256) void k_hred(
    const float* __restrict__ hpart, float* __restrict__ hsum, int NB) {
  __shared__ float sh[HD];
  const int t = threadIdx.x;
  const int col = t & (HD - 1);
  const int half = t >> 7;
  float acc = 0.0f;
  for (int r = blockIdx.x * 2 + half; r < NB; r += 128)
    acc += hpart[(size_t)r * HD + col];
  if (half) sh[col] = acc;
  __syncthreads();
  if (!half) atomicAdd(&hsum[col], acc + sh[col]);
}

// ---------------------------------------------------------------------------
// K3: terminator. ter = (hsum/N) . (ter_w[:H] + ter_w[H:]) + ter_b
// ---------------------------------------------------------------------------
__global__ __launch_bounds__(128) void k_ter(
    const float* __restrict__ hsum, const float* __restrict__ ter_w,
    const float* __restrict__ ter_b, float* __restrict__ out, float invN) {
  __shared__ float r2[2];
  const int t = threadIdx.x;
  float v = (hsum[t] * invN) * (ter_w[t] + ter_w[HD + t]);
#pragma unroll
  for (int o = 32; o > 0; o >>= 1) v += __shfl_down(v, o);
  if ((t & 63) == 0) r2[t >> 6] = v;
  __syncthreads();
  if (t == 0) out[0] = r2[0] + r2[1] + ter_b[0];
}

// ---------------------------------------------------------------------------
extern "C" void kernel_launch(void* const* d_in, const int* in_sizes, int n_in,
                              void* d_out, int out_size, void* d_ws, size_t ws_size,
                              hipStream_t stream) {
  const float* x        = (const float*)d_in[0];
  const float* pre_h    = (const float*)d_in[1];
  const float* edge_attr= (const float*)d_in[2];
  const float* enc_w    = (const float*)d_in[3];
  const float* enc_b    = (const float*)d_in[4];
  const float* M_w      = (const float*)d_in[5];
  const float* M_b      = (const float*)d_in[6];
  const float* U_w      = (const float*)d_in[7];
  const float* U_b      = (const float*)d_in[8];
  const float* dec_w    = (const float*)d_in[9];
  const float* dec_b    = (const float*)d_in[10];
  const float* ter_w    = (const float*)d_in[11];
  const float* ter_b    = (const float*)d_in[12];
  const int*   edge_idx = (const int*)d_in[13];

  const int N = in_sizes[0];      // 50000
  const int E = in_sizes[2];      // 600000
  const size_t NH = (size_t)N * HD;

  float* out = (float*)d_out;
  float* h_out = out;             // [0, N*H)
  float* y_out = out + NH;        // [N*H, N*H+N)
  float* ter_out = out + NH + N;

  // ws layout (bf16): zg | Pg | Qg | ag | cursor(N) | row_ptr(N) | partials(64)
  //                   | hsum(128) | epack(E int2) | encf | Pf | Qf | Uf | hpart
  unsigned short* zg = (unsigned short*)d_ws;
  unsigned short* Pg = zg + NH;
  unsigned short* Qg = Pg + NH;
  unsigned short* ag = Qg + NH;
  int*   cursor   = (int*)(ag + NH);
  int*   row_ptr  = cursor + N;
  int*   partials = row_ptr + N;
  float* hsum     = (float*)(partials + 64);
  int2*  epack    = (int2*)(hsum + HD);
  unsigned short* encf = (unsigned short*)(epack + E);
  unsigned short* Pf   = encf + 8 * 4 * 64 * 8;
  unsigned short* Qf   = Pf + 8 * 4 * 64 * 8;
  unsigned short* Uf   = Qf + 8 * 4 * 64 * 8;
  float* hpart = (float*)(Uf + 16 * 256 * 8);

  hipMemsetAsync(cursor, 0, (size_t)N * sizeof(int), stream);

  const int scan_blocks = (N + 1023) / 1024;  // 49
  const int eb = (E + 255) / 256;             // 2344
  const int nb32 = (N + 31) / 32;             // 1563

  k_frag_hist<<<40 + eb, 256, 0, stream>>>(enc_w, M_w, U_w, encf, Pf, Qf, Uf,
                                           edge_idx, cursor, E);
  k_scan_block<<<scan_blocks, 256, 0, stream>>>(cursor, row_ptr, partials,
                                                hsum, N);
  k_scan_add<<<scan_blocks, 256, 0, stream>>>(row_ptr, partials, cursor, N,
                                              scan_blocks);
  k_scatter_enc<<<eb + N / 16, 256, 0, stream>>>(
      edge_idx, edge_attr, cursor, epack, E, eb,
      x, pre_h, enc_w, enc_b, M_b, encf, Pf, Qf, zg, Pg, Qg);
  k_gather<<<nb32, 256, 0, stream>>>(
      Pg, Qg, M_w + 256 * HD, row_ptr, cursor, epack, ag, N);
  k_update<<<nb32, 256, 0, stream>>>(
      zg, ag, Uf, U_b, dec_w, dec_b, h_out, y_out, hpart, N);
  k_hred<<<64, 256, 0, stream>>>(hpart, hsum, nb32);
  k_ter<<<1, 128, 0, stream>>>(hsum, ter_w, ter_b, ter_out, 1.0f / (float)N);
}